// Round 1
// baseline (122.932 us; speedup 1.0000x reference)
//
#include <hip/hip_runtime.h>
#include <math.h>

// B=64, T=512, C=384, H=64. fp32 in/out; bf16 MFMA internally.
#define NB 64
#define NT 512
#define NC 384
#define NH 64

typedef __attribute__((ext_vector_type(8))) short bf16x8;
typedef __attribute__((ext_vector_type(4))) float f32x4;

__device__ __forceinline__ unsigned short f2bf(float f) {
  unsigned int u = __float_as_uint(f);
  return (unsigned short)((u + 0x7FFFu + ((u >> 16) & 1u)) >> 16);
}
// packed fp32x2 -> bf16x2 (RNE), single VALU op. lo in [15:0], hi in [31:16].
__device__ __forceinline__ unsigned int cvt_pk_bf16(float lo, float hi) {
  unsigned int r;
  asm("v_cvt_pk_bf16_f32 %0, %1, %2" : "=v"(r) : "v"(lo), "v"(hi));
  return r;
}

// ---------------------------------------------------------------------------
// Kernel 0: W[384][64] fp32 x3 -> Wt[192][384] bf16 (transposed, row-major)
// ---------------------------------------------------------------------------
__global__ __launch_bounds__(256) void wtrans_kernel(
    const float* __restrict__ Wq, const float* __restrict__ Wk,
    const float* __restrict__ Wv, unsigned short* __restrict__ Wt) {
  int id = blockIdx.x * 256 + threadIdx.x;
  if (id >= 3 * NC * NH) return;
  int m = id / (NC * NH);
  int r = id % (NC * NH);
  int c = r / NH;
  int h = r % NH;
  const float* W = (m == 0) ? Wq : ((m == 1) ? Wk : Wv);
  Wt[(m * NH + h) * NC + c] = f2bf(W[c * NH + h]);
}

// ---------------------------------------------------------------------------
// Kernel 1: fused QKV projection. M=32768, K=384, N=192.
// 384 threads = 6 waves; wave w owns N-tiles {2w, 2w+1} (w0-1: q, w2-3: k,
// w4-5: v). B-frags resident in VGPRs, loaded from L2 before the single
// barrier. Staging + epilogue use v_cvt_pk_bf16_f32 (1 op / 2 floats) instead
// of bit-twiddled f2bf (~10 ops / 2 floats) to keep the kernel HBM-bound.
// ---------------------------------------------------------------------------
#define XS 392  // 64 rows x 392 ushorts; 784 B row stride
__global__ __launch_bounds__(384, 3) void proj_kernel(
    const float* __restrict__ x, const unsigned short* __restrict__ Wt,
    unsigned short* __restrict__ q, unsigned short* __restrict__ k,
    unsigned short* __restrict__ vt) {
  __shared__ unsigned short xs[64 * XS];  // 50176 B
  const int t = threadIdx.x;  // 0..383
  const int m0 = blockIdx.x * 64;
  const int w = t / 64, l = t & 63, mi = l & 15, quad = l >> 4;

  // stage x tile: 64 rows x 384 fp32 -> bf16 (coalesced float4, packed cvt)
#pragma unroll 4
  for (int i = 0; i < 16; ++i) {
    int u = t + i * 384;  // 0..6143; row = u/96, 4-float seg = u%96
    int row = u / 96;
    int cp = (u % 96) * 4;
    float4 a = *(const float4*)(x + (size_t)(m0 + row) * NC + cp);
    uint2 bbu;
    bbu.x = cvt_pk_bf16(a.x, a.y);
    bbu.y = cvt_pk_bf16(a.z, a.w);
    *(uint2*)&xs[row * XS + cp] = bbu;
  }

  // wave-resident B-frags: tiles 2w, 2w+1 (issued before the barrier so L2
  // latency overlaps other waves' staging)
  bf16x8 bfr[2][12];
#pragma unroll
  for (int ntl = 0; ntl < 2; ++ntl) {
    const unsigned short* wr =
        Wt + (size_t)((w * 2 + ntl) * 16 + mi) * NC + quad * 8;
#pragma unroll
    for (int kc = 0; kc < 12; ++kc)
      bfr[ntl][kc] = *(const bf16x8*)(wr + kc * 32);
  }
  __syncthreads();

  f32x4 acc[2][4];  // [ntl][msub]
  const f32x4 zero = {0.f, 0.f, 0.f, 0.f};
#pragma unroll
  for (int i = 0; i < 2; ++i)
#pragma unroll
    for (int j = 0; j < 4; ++j) acc[i][j] = zero;

#pragma unroll
  for (int msub = 0; msub < 4; ++msub) {
#pragma unroll
    for (int kc = 0; kc < 12; ++kc) {
      bf16x8 a = *(const bf16x8*)&xs[(msub * 16 + mi) * XS + kc * 32 + quad * 8];
      acc[0][msub] =
          __builtin_amdgcn_mfma_f32_16x16x32_bf16(a, bfr[0][kc], acc[0][msub], 0, 0, 0);
      acc[1][msub] =
          __builtin_amdgcn_mfma_f32_16x16x32_bf16(a, bfr[1][kc], acc[1][msub], 0, 0, 0);
    }
  }

  // epilogue (no barriers, pure global stores).
  // C/D layout: col=mi (=n within tile), row=quad*4+r (=m). Tile = 2w+ntl;
  // matrix = tile>>2 (uniform per wave), h = (tile&3)*16 + mi.
  if (w < 4) {  // q (waves 0-1) / k (waves 2-3): scalar ushort stores
    unsigned short* dst = (w < 2) ? q : k;
    const float sc = (w < 2) ? 0.125f : 1.0f;  // fold 1/sqrt(64), exact
#pragma unroll
    for (int ntl = 0; ntl < 2; ++ntl) {
      int tile = w * 2 + ntl;
      int h = (tile & 3) * 16 + mi;
#pragma unroll
      for (int msub = 0; msub < 4; ++msub) {
        unsigned int u01 =
            cvt_pk_bf16(acc[ntl][msub][0] * sc, acc[ntl][msub][1] * sc);
        unsigned int u23 =
            cvt_pk_bf16(acc[ntl][msub][2] * sc, acc[ntl][msub][3] * sc);
        size_t base = (size_t)(m0 + msub * 16 + quad * 4) * NH + h;
        dst[base] = (unsigned short)u01;
        dst[base + NH] = (unsigned short)(u01 >> 16);
        dst[base + 2 * NH] = (unsigned short)u23;
        dst[base + 3 * NH] = (unsigned short)(u23 >> 16);
      }
    }
  } else {  // v (waves 4-5): 4 consecutive tokens per lane -> 8B store
    int bb = m0 >> 9, t0 = m0 & 511;
#pragma unroll
    for (int ntl = 0; ntl < 2; ++ntl) {
      int tile = w * 2 + ntl;
      int h = (tile & 3) * 16 + mi;
#pragma unroll
      for (int msub = 0; msub < 4; ++msub) {
        uint2 s_;
        s_.x = cvt_pk_bf16(acc[ntl][msub][0], acc[ntl][msub][1]);
        s_.y = cvt_pk_bf16(acc[ntl][msub][2], acc[ntl][msub][3]);
        *(uint2*)&vt[((size_t)bb * NH + h) * NT + t0 + msub * 16 + quad * 4] = s_;
      }
    }
  }
}

// ---------------------------------------------------------------------------
// Kernel 2: causal flash attention. ONE WAVE per (b, 16-row q-tile).
// NEW vs r4: (a) register double-buffered K/V tiles — next tile's 16 loads
// issue before current tile's softmax+PV, hiding L2 latency intra-wave
// (only 2 waves/SIMD, so TLP alone can't hide it); (b) alpha / inv broadcast
// via wave-local LDS (1 ds_write + 1 broadcast b128 read) replacing 4 serial
// ds_bpermute shuffles; (c) P-pack via v_cvt_pk_bf16_f32 (8 VALU ops vs ~88)
// on the LDS round-trip critical path. Zero barriers throughout.
// ---------------------------------------------------------------------------
#define PSTR 72
__global__ __launch_bounds__(64, 2) void attn_kernel(
    const unsigned short* __restrict__ q, const unsigned short* __restrict__ k,
    const unsigned short* __restrict__ vt, float* __restrict__ out) {
  __shared__ unsigned short ps[16 * PSTR];
  __shared__ __align__(16) float alpha_s[16];
  const int l = threadIdx.x;
  const int mi = l & 15, quad = l >> 4;
  const int bx = blockIdx.x;
  const int qi = 31 - (bx >> 6);  // heavy tiles first
  const int b = bx & 63;

  const unsigned short* qrow = q + ((size_t)b * NT + qi * 16 + mi) * NH;
  bf16x8 qb0 = *(const bf16x8*)(qrow + quad * 8);
  bf16x8 qb1 = *(const bf16x8*)(qrow + 32 + quad * 8);

  f32x4 accO[4];
  const f32x4 zero = {0.f, 0.f, 0.f, 0.f};
#pragma unroll
  for (int i = 0; i < 4; ++i) accO[i] = zero;
  float mrow = -INFINITY, lrow = 0.f;  // per-lane q-row = qi*16 + mi

  const unsigned short* kbase = k + (size_t)b * NT * NH;
  const unsigned short* vbase = vt + (size_t)b * NH * NT;
  const int ktmax = (qi * 16 + 15) >> 6;

  bf16x8 ka0A[4], ka1A[4], va0A[4], va1A[4];  // ping
  bf16x8 ka0B[4], ka1B[4], va0B[4], va1B[4];  // pong

#define LOADKV(KA0, KA1, VA0, VA1, KT)                                        \
  {                                                                           \
    const unsigned short* kb_ = kbase + (size_t)(KT) * 64 * NH;               \
    const unsigned short* vb_ = vbase + (KT) * 64;                            \
    _Pragma("unroll") for (int nt_ = 0; nt_ < 4; ++nt_) {                     \
      const unsigned short* kr_ =                                             \
          kb_ + (size_t)(nt_ * 16 + mi) * NH + quad * 8;                      \
      KA0[nt_] = *(const bf16x8*)kr_;                                         \
      KA1[nt_] = *(const bf16x8*)(kr_ + 32);                                  \
      const unsigned short* vr_ =                                             \
          vb_ + (size_t)(nt_ * 16 + mi) * NT + quad * 8;                      \
      VA0[nt_] = *(const bf16x8*)vr_;                                         \
      VA1[nt_] = *(const bf16x8*)(vr_ + 32);                                  \
    }                                                                         \
  }

#define COMPUTE(KA0, KA1, VA0, VA1, KT)                                       \
  {                                                                           \
    /* S^T tile: A = K rows (m=key), B = Q rows (n=q). */                     \
    float p_[4][4];                                                           \
    _Pragma("unroll") for (int nt_ = 0; nt_ < 4; ++nt_) {                     \
      f32x4 z_ = zero;                                                        \
      z_ = __builtin_amdgcn_mfma_f32_16x16x32_bf16(KA0[nt_], qb0, z_, 0, 0, 0); \
      z_ = __builtin_amdgcn_mfma_f32_16x16x32_bf16(KA1[nt_], qb1, z_, 0, 0, 0); \
      _Pragma("unroll") for (int r_ = 0; r_ < 4; ++r_) p_[nt_][r_] = z_[r_];  \
    }                                                                         \
    if ((KT) == ktmax) { /* causal mask on diagonal tile */                   \
      _Pragma("unroll") for (int nt_ = 0; nt_ < 4; ++nt_)                     \
          _Pragma("unroll") for (int r_ = 0; r_ < 4; ++r_)                    \
              if ((KT)*64 + nt_ * 16 + quad * 4 + r_ > qi * 16 + mi)          \
        p_[nt_][r_] = -INFINITY;                                              \
    }                                                                         \
    float vmax_ = -INFINITY;                                                  \
    _Pragma("unroll") for (int nt_ = 0; nt_ < 4; ++nt_)                       \
        _Pragma("unroll") for (int r_ = 0; r_ < 4; ++r_)                      \
            vmax_ = fmaxf(vmax_, p_[nt_][r_]);                                \
    vmax_ = fmaxf(vmax_, __shfl_xor(vmax_, 16));                              \
    vmax_ = fmaxf(vmax_, __shfl_xor(vmax_, 32));                              \
    float mn_ = fmaxf(mrow, vmax_);                                           \
    float alpha_ = __expf(mrow - mn_);                                        \
    mrow = mn_;                                                               \
    float rsum_ = 0.f;                                                        \
    _Pragma("unroll") for (int nt_ = 0; nt_ < 4; ++nt_)                       \
        _Pragma("unroll") for (int r_ = 0; r_ < 4; ++r_) {                    \
      p_[nt_][r_] = __expf(p_[nt_][r_] - mn_);                                \
      rsum_ += p_[nt_][r_];                                                   \
    }                                                                         \
    rsum_ += __shfl_xor(rsum_, 16);                                           \
    rsum_ += __shfl_xor(rsum_, 32);                                           \
    lrow = lrow * alpha_ + rsum_;                                             \
    /* alpha broadcast + P -> LDS (wave-local, no barrier) */                 \
    if (quad == 0) alpha_s[mi] = alpha_;                                      \
    _Pragma("unroll") for (int nt_ = 0; nt_ < 4; ++nt_) {                     \
      uint2 pk_;                                                              \
      pk_.x = cvt_pk_bf16(p_[nt_][0], p_[nt_][1]);                            \
      pk_.y = cvt_pk_bf16(p_[nt_][2], p_[nt_][3]);                            \
      *(uint2*)&ps[mi * PSTR + nt_ * 16 + quad * 4] = pk_;                    \
    }                                                                         \
    bf16x8 pa0_ = *(const bf16x8*)&ps[mi * PSTR + quad * 8];                  \
    bf16x8 pa1_ = *(const bf16x8*)&ps[mi * PSTR + 32 + quad * 8];             \
    f32x4 av_ = *(const f32x4*)&alpha_s[quad * 4];                            \
    _Pragma("unroll") for (int hi_ = 0; hi_ < 4; ++hi_)                       \
        _Pragma("unroll") for (int r_ = 0; r_ < 4; ++r_)                      \
            accO[hi_][r_] *= av_[r_];                                         \
    /* O += P V  (A = P rows, B = V^T rows; D col=h, row=q) */                \
    _Pragma("unroll") for (int hi_ = 0; hi_ < 4; ++hi_) {                     \
      accO[hi_] = __builtin_amdgcn_mfma_f32_16x16x32_bf16(pa0_, VA0[hi_],     \
                                                          accO[hi_], 0, 0, 0); \
      accO[hi_] = __builtin_amdgcn_mfma_f32_16x16x32_bf16(pa1_, VA1[hi_],     \
                                                          accO[hi_], 0, 0, 0); \
    }                                                                         \
  }

  // software-pipelined main loop: tile kt+1's loads in flight during tile
  // kt's softmax+PV. Ping-pong register sets; all indices compile-time.
  LOADKV(ka0A, ka1A, va0A, va1A, 0);
  int kt = 0;
  while (kt < ktmax) {
    LOADKV(ka0B, ka1B, va0B, va1B, kt + 1);
    COMPUTE(ka0A, ka1A, va0A, va1A, kt);
    ++kt;
    if (kt < ktmax) {
      LOADKV(ka0A, ka1A, va0A, va1A, kt + 1);
      COMPUTE(ka0B, ka1B, va0B, va1B, kt);
      ++kt;
    } else {
      COMPUTE(ka0B, ka1B, va0B, va1B, kt);
      ++kt;
    }
  }
  if (kt == ktmax) COMPUTE(ka0A, ka1A, va0A, va1A, kt);

  // epilogue: inv broadcast via LDS (ordered after last COMPUTE's alpha use)
  float inv = 1.f / lrow;
  if (quad == 0) alpha_s[mi] = inv;
  f32x4 iv4 = *(const f32x4*)&alpha_s[quad * 4];
  const size_t obase = ((size_t)b * NT + qi * 16) * NH;
#pragma unroll
  for (int r = 0; r < 4; ++r) {
#pragma unroll
    for (int hi = 0; hi < 4; ++hi)
      out[obase + (size_t)(quad * 4 + r) * NH + hi * 16 + mi] =
          accO[hi][r] * iv4[r];
  }
#undef LOADKV
#undef COMPUTE
}

extern "C" void kernel_launch(void* const* d_in, const int* in_sizes, int n_in,
                              void* d_out, int out_size, void* d_ws, size_t ws_size,
                              hipStream_t stream) {
  const float* x  = (const float*)d_in[0];
  const float* Wq = (const float*)d_in[1];
  const float* Wk = (const float*)d_in[2];
  const float* Wv = (const float*)d_in[3];

  unsigned short* Wt = (unsigned short*)d_ws;          // 192*384
  unsigned short* qb = Wt + 192 * 384;                 // 32768*64 each
  unsigned short* kb = qb + 32768 * 64;
  unsigned short* vtb = kb + 32768 * 64;               // Vt[b][h][t]
  float* out = (float*)d_out;

  wtrans_kernel<<<288, 256, 0, stream>>>(Wq, Wk, Wv, Wt);
  proj_kernel<<<512, 384, 0, stream>>>(x, Wt, qb, kb, vtb);
  attn_kernel<<<2048, 64, 0, stream>>>(qb, kb, vtb, out);
}